// Round 8
// baseline (1024.058 us; speedup 1.0000x reference)
//
#include <hip/hip_runtime.h>

#define DEG 16
#define E12 12
#define MAX_ITERS 32
#define BLK 1024
#define CHF 25000          // chunk floats (100 KB LDS)
#define NPBMAX 4096        // max nodes per block (12-bit dst)

// ---------------------------------------------------------------------------
// sc0 ops: agent-scope relaxed -> L1-bypassing, L2-fresh, no fence codegen.
// ---------------------------------------------------------------------------
__device__ __forceinline__ float ld_sc0(const float* p) {
    return __hip_atomic_load((float*)p, __ATOMIC_RELAXED, __HIP_MEMORY_SCOPE_AGENT);
}
__device__ __forceinline__ void st_sc0(float* p, float v) {
    __hip_atomic_store(p, v, __ATOMIC_RELAXED, __HIP_MEMORY_SCOPE_AGENT);
}
__device__ __forceinline__ unsigned ld_u32_sc0(const unsigned* p) {
    return __hip_atomic_load((unsigned*)p, __ATOMIC_RELAXED, __HIP_MEMORY_SCOPE_AGENT);
}
__device__ __forceinline__ void st_u32_sc0(unsigned* p, unsigned v) {
    __hip_atomic_store(p, v, __ATOMIC_RELAXED, __HIP_MEMORY_SCOPE_AGENT);
}

__device__ __forceinline__ int get_xcd() {
    unsigned x;
    asm volatile("s_getreg_b32 %0, hwreg(HW_REG_XCC_ID)" : "=s"(x));
    return (int)(x & 7u);
}

// global barrier (prologue / slow path)
__device__ __forceinline__ void grid_barrier(unsigned* cnt, unsigned* gen,
                                             unsigned target, unsigned nblocks) {
    __syncthreads();
    if (threadIdx.x == 0) {
        __threadfence();
        unsigned arrived = __hip_atomic_fetch_add(cnt, 1u, __ATOMIC_ACQ_REL,
                                                  __HIP_MEMORY_SCOPE_AGENT);
        if (arrived == nblocks - 1u) {
            __hip_atomic_store(cnt, 0u, __ATOMIC_RELAXED, __HIP_MEMORY_SCOPE_AGENT);
            __hip_atomic_fetch_add(gen, 1u, __ATOMIC_RELEASE, __HIP_MEMORY_SCOPE_AGENT);
        } else {
            while (__hip_atomic_load(gen, __ATOMIC_RELAXED,
                                     __HIP_MEMORY_SCOPE_AGENT) < target)
                __builtin_amdgcn_s_sleep(2);
        }
        __threadfence();
    }
    __syncthreads();
}

// XCD-local barrier (R6-proven; no cache maintenance in codegen)
__device__ __forceinline__ void xcd_barrier(unsigned* cnt, unsigned* gen,
                                            unsigned target, unsigned nblocks) {
    __syncthreads();
    if (threadIdx.x == 0) {
        unsigned arrived = __hip_atomic_fetch_add(cnt, 1u, __ATOMIC_RELEASE,
                                                  __HIP_MEMORY_SCOPE_WORKGROUP);
        if (arrived == nblocks - 1u) {
            __hip_atomic_store(cnt, 0u, __ATOMIC_RELAXED,
                               __HIP_MEMORY_SCOPE_WORKGROUP);
            __hip_atomic_fetch_add(gen, 1u, __ATOMIC_RELEASE,
                                   __HIP_MEMORY_SCOPE_WORKGROUP);
        } else {
            while (ld_u32_sc0(gen) < target)
                __builtin_amdgcn_s_sleep(2);
        }
    }
    __syncthreads();
}

__device__ __forceinline__ void softmax_row(const float* __restrict__ fp,
                                            const int* __restrict__ adj,
                                            float* __restrict__ wout,
                                            size_t base, int N) {
    const float4* f4 = (const float4*)(fp + base);
    const int4*   a4 = (const int4*)(adj + base);
    float v[DEG];
#pragma unroll
    for (int k = 0; k < DEG / 4; ++k) {
        float4 f = f4[k];
        int4   a = a4[k];
        v[4*k+0] = (a.x == N) ? f.x - 1e7f : f.x;
        v[4*k+1] = (a.y == N) ? f.y - 1e7f : f.y;
        v[4*k+2] = (a.z == N) ? f.z - 1e7f : f.z;
        v[4*k+3] = (a.w == N) ? f.w - 1e7f : f.w;
    }
    float m = v[0];
#pragma unroll
    for (int j = 1; j < DEG; ++j) m = fmaxf(m, v[j]);
    float s = 0.f;
#pragma unroll
    for (int j = 0; j < DEG; ++j) { v[j] = __expf(v[j] - m); s += v[j]; }
    float inv = 1.f / s;
    float4* w4 = (float4*)(wout + base);
#pragma unroll
    for (int k = 0; k < DEG / 4; ++k) {
        float4 o;
        o.x = v[4*k+0] * inv;
        o.y = v[4*k+1] * inv;
        o.z = v[4*k+2] * inv;
        o.w = v[4*k+3] * inv;
        w4[k] = o;
    }
}

__device__ __forceinline__ float node_acc12(const int* __restrict__ es,
                                            const float* __restrict__ ew,
                                            const float* __restrict__ Rc) {
    const int4*   s4 = (const int4*)es;
    const float4* w4 = (const float4*)ew;
    int4 a = s4[0], b = s4[1], c = s4[2];
    float4 x = w4[0], y = w4[1], z = w4[2];
    float acc;
    acc  = x.x * Rc[a.x];  acc += x.y * Rc[a.y];
    acc += x.z * Rc[a.z];  acc += x.w * Rc[a.w];
    acc += y.x * Rc[b.x];  acc += y.y * Rc[b.y];
    acc += y.z * Rc[b.z];  acc += y.w * Rc[b.w];
    acc += z.x * Rc[c.x];  acc += z.y * Rc[c.y];
    acc += z.z * Rc[c.z];  acc += z.w * Rc[c.w];
    return acc;
}

__device__ __forceinline__ void scale_row(float* __restrict__ wout, int g, float r) {
    float4* w4 = (float4*)(wout + (size_t)g * DEG);
#pragma unroll
    for (int k = 0; k < DEG / 4; ++k) {
        float4 v = w4[k];
        v.x *= r; v.y *= r; v.z *= r; v.w *= r;
        w4[k] = v;
    }
}

// ===========================================================================
// FUSED v8: per-XCD redundant batch compute, XCD-local barriers. Rounds:
//   1) stage full batch R (coalesced sc0, local L2) into 100 KB LDS chunks
//   2) scatter-accumulate exact counting-sorted edge stream into an LDS
//      accumulator via ds_add_f32 (zero padding -> no overflow slow-path)
//   3) readback relu(acc - d), publish, xcd_barrier
// No device-scope fences in the round loop. Slow path: E12 direct gathers +
// global barriers (flag-agreed at global barriers).
// ===========================================================================
__global__ __launch_bounds__(BLK, 4)
void fused8_k(const float* __restrict__ fp, const int* __restrict__ adj,
              const int* __restrict__ in_idx, const float* __restrict__ dem,
              const int* __restrict__ nn, float* __restrict__ wout,
              char* __restrict__ wsb, int nodes) {
    __shared__ float ldsChunk[CHF];
    __shared__ float accL[NPBMAX];
    __shared__ int s_xcd, s_rank, s_mode, s_part;
    __shared__ int s_cnt[4], s_cur[4], s_offE[5];

    unsigned* g_cnt  = (unsigned*)(wsb);
    unsigned* g_gen  = (unsigned*)(wsb + 128);
    unsigned* blkcnt = (unsigned*)(wsb + 2304);   // [8]
    unsigned* ovf    = (unsigned*)(wsb + 2432);
    int*   e_src  = (int*)(wsb + 4096);
    float* e_w    = (float*)(wsb + 4096 + (size_t)nodes * E12 * 4);
    float* Rf0    = (float*)((char*)e_w + (size_t)nodes * E12 * 4);
    float* Rf1    = Rf0 + nodes;
    float* slices = Rf1 + nodes;                  // 16 x N floats
    uint2* streams = (uint2*)((char*)slices + (size_t)nodes * 16);

    const int N   = *nn;
    const int tid = (int)threadIdx.x;
    const int T   = (int)gridDim.x * BLK;
    const unsigned nblocks = gridDim.x;
    unsigned gb = 0;

    // ---- self-organize ----
    if (tid == 0) {
        int x = get_xcd();
        s_xcd  = x;
        s_rank = (int)__hip_atomic_fetch_add(&blkcnt[x], 1u, __ATOMIC_RELAXED,
                                             __HIP_MEMORY_SCOPE_AGENT);
    }
    __syncthreads();
    const int my_xcd  = s_xcd;
    const int my_rank = s_rank;

    // ---- P0: softmax ----
#pragma unroll
    for (int rep = 0; rep < 2; ++rep) {
        int g = (int)blockIdx.x * BLK + tid + rep * T;
        if (g < nodes) softmax_row(fp, adj, wout, (size_t)g * DEG, N);
    }
    grid_barrier(g_cnt, g_gen, ++gb, nblocks);

    // ---- P1: E12 compaction + validity checks ----
#pragma unroll
    for (int rep = 0; rep < 2; ++rep) {
        int g = (int)blockIdx.x * BLK + tid + rep * T;
        if (g >= nodes) continue;
        const int gbat = g / N;
        const int4* t4 = (const int4*)(in_idx + (size_t)g * 48);
        int cb[16], cs[16], cl[16];
#pragma unroll
        for (int q = 0; q < 4; ++q) {
            int4 qa = t4[3*q + 0];
            int4 qb = t4[3*q + 1];
            int4 qc = t4[3*q + 2];
            cb[4*q+0] = qa.x; cs[4*q+0] = qa.y; cl[4*q+0] = qa.z;
            cb[4*q+1] = qa.w; cs[4*q+1] = qb.x; cl[4*q+1] = qb.y;
            cb[4*q+2] = qb.z; cs[4*q+2] = qb.w; cl[4*q+2] = qc.x;
            cb[4*q+3] = qc.y; cs[4*q+3] = qc.z; cl[4*q+3] = qc.w;
        }
        float cw[16];
#pragma unroll
        for (int k = 0; k < 16; ++k)
            cw[k] = wout[((size_t)cb[k] * N + cs[k]) * DEG + cl[k]];
        bool bad = (cw[12] != 0.f) || (cw[13] != 0.f) ||
                   (cw[14] != 0.f) || (cw[15] != 0.f);
#pragma unroll
        for (int k = 0; k < E12; ++k)
            bad = bad || (cb[k] != gbat) || ((unsigned)cs[k] >= (unsigned)N);
        if (bad) st_u32_sc0(ovf, 1u);
        int4*   es4 = (int4*)(e_src + (size_t)g * E12);
        float4* ew4 = (float4*)(e_w + (size_t)g * E12);
        es4[0] = make_int4(cs[0], cs[1], cs[2], cs[3]);   // batch-LOCAL srcs
        es4[1] = make_int4(cs[4], cs[5], cs[6], cs[7]);
        es4[2] = make_int4(cs[8], cs[9], cs[10], cs[11]);
        ew4[0] = make_float4(cw[0], cw[1], cw[2], cw[3]);
        ew4[1] = make_float4(cw[4], cw[5], cw[6], cw[7]);
        ew4[2] = make_float4(cw[8], cw[9], cw[10], cw[11]);
    }
    grid_barrier(g_cnt, g_gen, ++gb, nblocks);

    // ---- mode decision (globally consistent: inputs fixed after GB2) ----
    const int npb   = (N + 31) >> 5;
    const int nch   = (N + CHF - 1) / CHF;
    const int chunk = (nch > 0) ? (N + nch - 1) / nch : 1;
    if (tid == 0) {
        unsigned cc[8];
#pragma unroll
        for (int x = 0; x < 8; ++x) cc[x] = ld_u32_sc0(&blkcnt[x]);
        bool ok = (4 * N == nodes) && (N > 0) && (npb <= NPBMAX) &&
                  (nch >= 1) && (nch <= 4) && (chunk <= CHF) &&
                  (chunk < 32768) && (ld_u32_sc0(ovf) == 0u);
#pragma unroll
        for (int p = 0; p < 4; ++p)
            ok = ok && (cc[2*p] >= 32u || cc[2*p+1] >= 32u);
        s_mode = ok ? 1 : 0;
        s_part = (ok && cc[my_xcd] >= 32u && my_rank < 32) ? 1 : 0;
    }
    __syncthreads();

    if (s_mode == 1) {
        if (s_part != 1) return;            // not counted in any later barrier
        const int batch = my_xcd >> 1;
        const int lb = my_rank * npb;
        const int le = min(lb + npb, N);
        uint2* stream = streams + (size_t)(my_xcd * 32 + my_rank) * (NPBMAX * E12);

        // ---- build exact counting-sorted edge stream (private to block) ----
        if (tid < 4) { s_cnt[tid] = 0; }
        __syncthreads();
        int   myl[4];  bool mya[4];  float d[4];
#pragma unroll
        for (int s = 0; s < 4; ++s) {
            int l = lb + s * BLK + tid;
            myl[s] = l; mya[s] = (l < le); d[s] = 0.f;
            if (mya[s]) {
                d[s] = dem[batch * N + l];
                const int* es = e_src + (size_t)(batch * N + l) * E12;
#pragma unroll
                for (int k = 0; k < E12; ++k)
                    atomicAdd(&s_cnt[es[k] / chunk], 1);
            }
        }
        __syncthreads();
        if (tid == 0) {
            s_offE[0] = 0;
#pragma unroll
            for (int c = 0; c < 4; ++c) s_offE[c + 1] = s_offE[c] + s_cnt[c];
#pragma unroll
            for (int c = 0; c < 4; ++c) s_cur[c] = s_offE[c];
        }
        __syncthreads();
#pragma unroll
        for (int s = 0; s < 4; ++s) {
            if (!mya[s]) continue;
            int g = batch * N + myl[s];
            const int*   es = e_src + (size_t)g * E12;
            const float* ew = e_w + (size_t)g * E12;
            int dst = myl[s] - lb;
#pragma unroll
            for (int k = 0; k < E12; ++k) {
                int src = es[k];
                int c = src / chunk;
                int pos = atomicAdd(&s_cur[c], 1);
                stream[pos] = make_uint2(((unsigned)dst << 15) |
                                         (unsigned)(src - c * chunk),
                                         __float_as_uint(ew[k]));
            }
        }
        __syncthreads();

        // ---- rounds ----
        unsigned* xc = (unsigned*)(wsb + 256 + my_xcd * 256);
        unsigned* xg = (unsigned*)(wsb + 256 + my_xcd * 256 + 128);
        unsigned xb = 0;
        float* bufA = slices + (size_t)(2 * my_xcd + 0) * N;
        float* bufB = slices + (size_t)(2 * my_xcd + 1) * N;

        float rr[4];
#pragma unroll
        for (int s = 0; s < 4; ++s) {
            rr[s] = fmaxf(-d[s], 0.f);
            if (mya[s]) st_sc0(bufA + myl[s], rr[s]);
        }
        xcd_barrier(xc, xg, ++xb, 32u);

        float* Rin  = bufA;
        float* Rout = bufB;
        for (int t = 1; t < MAX_ITERS; ++t) {
            for (int i = tid; i < npb; i += BLK) accL[i] = 0.f;
            for (int c = 0; c < nch; ++c) {
                const int cbase = c * chunk;
                const int ce = min(chunk, N - cbase);
                for (int i = tid; i < ce; i += BLK)
                    ldsChunk[i] = ld_sc0(Rin + cbase + i);
                __syncthreads();
                const int ee = s_offE[c + 1];
                for (int e = s_offE[c] + tid; e < ee; e += BLK) {
                    uint2 pr = stream[e];
                    atomicAdd(&accL[pr.x >> 15],
                              __uint_as_float(pr.y) * ldsChunk[pr.x & 0x7FFFu]);
                }
                __syncthreads();
            }
#pragma unroll
            for (int s = 0; s < 4; ++s)
                if (mya[s]) rr[s] = fmaxf(accL[myl[s] - lb] - d[s], 0.f);
            if (t < MAX_ITERS - 1) {
#pragma unroll
                for (int s = 0; s < 4; ++s)
                    if (mya[s]) st_sc0(Rout + myl[s], rr[s]);
                xcd_barrier(xc, xg, ++xb, 32u);
                float* tmp = Rin; Rin = Rout; Rout = tmp;
            }
        }

        // ---- epilogue (twin XCDs write identical values -> benign) ----
#pragma unroll
        for (int s = 0; s < 4; ++s)
            if (mya[s]) scale_row(wout, batch * N + myl[s], rr[s]);
        return;
    }

    // ---- SLOW: E12 direct gathers + global barriers ----
    {
        int g0 = (int)blockIdx.x * BLK + tid;
        int g1 = g0 + T;
        bool a0 = (g0 < nodes), a1 = (g1 < nodes);
        float d0 = a0 ? dem[g0] : 0.f;
        float d1 = a1 ? dem[g1] : 0.f;
        int base0 = a0 ? (g0 / N) * N : 0;
        int base1 = a1 ? (g1 / N) * N : 0;
        float r0 = fmaxf(-d0, 0.f), r1 = fmaxf(-d1, 0.f);
        if (a0) Rf0[g0] = r0;
        if (a1) Rf0[g1] = r1;
        grid_barrier(g_cnt, g_gen, ++gb, nblocks);
        const float* Rc = Rf0;
        float*       Rn = Rf1;
        for (int t = 1; t < MAX_ITERS; ++t) {
            if (a0) r0 = fmaxf(node_acc12(e_src + (size_t)g0 * E12,
                                          e_w + (size_t)g0 * E12,
                                          Rc + base0) - d0, 0.f);
            if (a1) r1 = fmaxf(node_acc12(e_src + (size_t)g1 * E12,
                                          e_w + (size_t)g1 * E12,
                                          Rc + base1) - d1, 0.f);
            if (t < MAX_ITERS - 1) {
                if (a0) Rn[g0] = r0;
                if (a1) Rn[g1] = r1;
                grid_barrier(g_cnt, g_gen, ++gb, nblocks);
                float* tmp = (float*)Rc; Rc = Rn; Rn = tmp;
            }
        }
        if (a0) scale_row(wout, g0, r0);
        if (a1) scale_row(wout, g1, r1);
    }
}

// ===========================================================================
// HOST FALLBACK (round-1 kernels, known-correct)
// ===========================================================================
__global__ void softmax_k(const float* __restrict__ fp, const int* __restrict__ adj,
                          const int* __restrict__ nn, float* __restrict__ wout,
                          int nodes) {
    int i = blockIdx.x * blockDim.x + threadIdx.x;
    if (i >= nodes) return;
    softmax_row(fp, adj, wout, (size_t)i * DEG, *nn);
}

__global__ void gather_k(const int* __restrict__ in_idx, const float* __restrict__ w,
                         const int* __restrict__ nn, int* __restrict__ e_srcO,
                         float* __restrict__ e_wO, int edges) {
    int e = blockIdx.x * blockDim.x + threadIdx.x;
    if (e >= edges) return;
    const int N = *nn;
    size_t e3 = 3 * (size_t)e;
    int fi = in_idx[e3] * N + in_idx[e3 + 1];
    e_srcO[e] = fi;
    e_wO[e]   = w[(size_t)fi * DEG + in_idx[e3 + 2]];
}

__global__ void iter_k(const int* __restrict__ e_srcO, const float* __restrict__ e_wO,
                       const float* __restrict__ dem, const float* __restrict__ Rin,
                       float* __restrict__ Rout, int nodes) {
    int i = blockIdx.x * blockDim.x + threadIdx.x;
    if (i >= nodes) return;
    const size_t base = (size_t)i * DEG;
    const int4*   s4 = (const int4*)(e_srcO + base);
    const float4* w4 = (const float4*)(e_wO + base);
    float acc = 0.f;
#pragma unroll
    for (int k = 0; k < DEG / 4; ++k) {
        int4   s = s4[k];
        float4 w = w4[k];
        acc += w.x * Rin[s.x];
        acc += w.y * Rin[s.y];
        acc += w.z * Rin[s.z];
        acc += w.w * Rin[s.w];
    }
    float r = acc - dem[i];
    Rout[i] = r > 0.f ? r : 0.f;
}

__global__ void final_k(const float* __restrict__ w, const float* __restrict__ R,
                        float* __restrict__ out, int nodes) {
    int i = blockIdx.x * blockDim.x + threadIdx.x;
    if (i >= nodes) return;
    scale_row((float*)w, i, R[i]);
    (void)out;
}

extern "C" void kernel_launch(void* const* d_in, const int* in_sizes, int n_in,
                              void* d_out, int out_size, void* d_ws, size_t ws_size,
                              hipStream_t stream) {
    const float* fp  = (const float*)d_in[0];
    const float* dem = (const float*)d_in[1];
    const int*   adj = (const int*)d_in[2];
    const int*   idx = (const int*)d_in[3];
    const int*   nn  = (const int*)d_in[4];

    const int edges = in_sizes[0];   // B*N*D
    const int nodes = in_sizes[1];   // B*N

    float* weights = (float*)d_out;
    char*  ws      = (char*)d_ws;

    int dev = 0, cus = 0, maxBlk = 0;
    hipGetDevice(&dev);
    hipDeviceGetAttribute(&cus, hipDeviceAttributeMultiprocessorCount, dev);
    hipOccupancyMaxActiveBlocksPerMultiprocessor(&maxBlk, (const void*)fused8_k,
                                                 BLK, 0);

    // ws: 4096 | e_src 48n | e_w 48n | Rf 8n | slices 16n | streams 256*NPBMAX*12*8
    const size_t need = 4096 + (size_t)nodes * (E12 * 8 + 8 + 16)
                      + (size_t)256 * NPBMAX * E12 * 8;
    const int grid = cus;

    const bool fused_ok = (maxBlk >= 1) && (cus >= 16) &&
                          ((long long)grid * BLK * 2 >= nodes) &&
                          (ws_size >= need) && (nodes % 4 == 0);

    if (fused_ok) {
        hipMemsetAsync(ws, 0, 4096, stream);
        void* args[] = { (void*)&fp, (void*)&adj, (void*)&idx, (void*)&dem,
                         (void*)&nn, (void*)&weights, (void*)&ws, (void*)&nodes };
        hipLaunchCooperativeKernel((const void*)fused8_k, dim3(grid), dim3(BLK),
                                   args, 0, stream);
    } else {
        int*   e_srcO = (int*)ws;
        float* e_wO   = (float*)(ws + (size_t)edges * sizeof(int));
        float* R0     = (float*)(ws + (size_t)edges * 8);
        float* R1     = R0 + nodes;
        const int blk = 256;
        const int gn = (nodes + blk - 1) / blk;
        const int ge = (edges + blk - 1) / blk;
        hipMemsetAsync(R0, 0, (size_t)nodes * sizeof(float), stream);
        softmax_k<<<gn, blk, 0, stream>>>(fp, adj, nn, weights, nodes);
        gather_k<<<ge, blk, 0, stream>>>(idx, weights, nn, e_srcO, e_wO, edges);
        float* a = R0;
        float* b = R1;
        for (int t = 0; t < MAX_ITERS; ++t) {
            iter_k<<<gn, blk, 0, stream>>>(e_srcO, e_wO, dem, a, b, nodes);
            float* tmp = a; a = b; b = tmp;
        }
        final_k<<<gn, blk, 0, stream>>>(weights, a, (float*)d_out, nodes);
    }
}